// Round 6
// baseline (2610.969 us; speedup 1.0000x reference)
//
#include <hip/hip_runtime.h>
#include <stdint.h>

// ---------------- problem constants ----------------
#define EDIM   300      // hidden/embed dim
#define KPAD   320      // padded K for MFMA GEMMs
#define NG     1200     // 4*EDIM gates
#define NB     64       // batch
#define SENC   64       // encoder steps
#define SDEC   63       // decoder steps
#define ZHV    12016
#define DROWS  4032     // NB*SDEC
#define MPAD   4096
#define HXW    10240    // u32 words per h slot: 64 rows x 160 jp ([row][jp])
#define NSL    20       // j-slices / waves

typedef unsigned short u16;
typedef __attribute__((ext_vector_type(8))) short bf16x8;
typedef __attribute__((ext_vector_type(4))) float f32x4;

static __device__ __forceinline__ u16 f2bf(float f){
  uint32_t u = __builtin_bit_cast(uint32_t, f);
  return (u16)((u + 0x7fffu + ((u >> 16) & 1u)) >> 16);
}
static __device__ __forceinline__ float sigm(float x){ return 1.f/(1.f + __expf(-x)); }
static __device__ __forceinline__ float tanhf_(float x){
  x = fminf(fmaxf(x, -15.f), 15.f);
  float e = __expf(2.f*x);
  return (e - 1.f)/(e + 1.f);
}

// ---------------- workspace init ----------------
__global__ void zero_kernel(float4* p, long n){
  long i = (long)blockIdx.x*blockDim.x + threadIdx.x;
  long st = (long)gridDim.x*blockDim.x;
  float4 z = {0.f,0.f,0.f,0.f};
  for (; i < n; i += st) p[i] = z;
}

// ---------------- Whh (1200x300) f32 -> MFMA A-fragment tiles bf16 ----------------
// frag = ((slice*4 + gate)*10 + kc); elem (lane*8 + e) = Whh[g*300 + slice*16 + (lane&15)]
//                                                          [kc*32 + (lane>>4)*8 + e], 0-padded.
__global__ void build_wa(const float* __restrict__ W, u16* __restrict__ out){
  int idx = blockIdx.x*blockDim.x + threadIdx.x;
  if (idx >= NSL*4*10*512) return;
  int e    = idx & 7;
  int lane = (idx >> 3) & 63;
  int frag = idx >> 9;
  int kc = frag % 10;
  int g  = (frag / 10) & 3;
  int s  = frag / 40;
  int j = s*16 + (lane & 15);
  int k = kc*32 + ((lane >> 4) << 3) + e;
  float f = (j < EDIM && k < EDIM) ? W[(size_t)(g*EDIM + j)*EDIM + k] : 0.f;
  out[idx] = f2bf(f);
}

// ---------------- weight repack: (N x 300) f32 -> (Npad x 320) bf16 ----------------
__global__ void build_b(const float* __restrict__ W, u16* __restrict__ out, int N){
  int idx = blockIdx.x*blockDim.x + threadIdx.x;
  if (idx >= N*EDIM) return;
  int n = idx / EDIM, k = idx - n*EDIM;
  out[(size_t)n*KPAD + k] = f2bf(W[idx]);
}

// ---------------- embeddings -> padded bf16 A operands ----------------
__global__ void embed_en(const int* __restrict__ ids, const float* __restrict__ emb, u16* __restrict__ x){
  int idx = blockIdx.x*blockDim.x + threadIdx.x;
  if (idx >= MPAD*EDIM) return;
  int r = idx / EDIM, k = idx - r*EDIM;
  x[(size_t)r*KPAD + k] = f2bf(emb[(size_t)ids[r]*EDIM + k]);
}
__global__ void embed_zh(const int* __restrict__ zh, const float* __restrict__ emb, u16* __restrict__ x){
  int idx = blockIdx.x*blockDim.x + threadIdx.x;
  if (idx >= DROWS*EDIM) return;
  int r = idx / EDIM, k = idx - r*EDIM;
  int b = r / SDEC, t = r - b*SDEC;
  x[(size_t)r*KPAD + k] = f2bf(emb[(size_t)zh[b*SENC + t]*EDIM + k]);
}

// ---------------- bf16 MFMA GEMM: C[m,n] = sum_k A[m,k]*B[n,k] (+bias[n]) ----------------
#define LDT 40   // LDS row stride in bf16 elems (80 B)
__global__ __launch_bounds__(256) void gemm_nt(const u16* __restrict__ A, const u16* __restrict__ B,
                float* __restrict__ C, int ldc, int Mreal, int Nreal, const float* __restrict__ bias){
  __shared__ __align__(16) u16 As[128*LDT];
  __shared__ __align__(16) u16 Bs[128*LDT];
  int tid = threadIdx.x;
  int lane = tid & 63, wave = tid >> 6;
  int wm = wave >> 1, wn = wave & 1;
  int m0 = blockIdx.y*128, n0 = blockIdx.x*128;
  f32x4 acc[4][4];
  for (int i=0;i<4;i++) for (int j=0;j<4;j++) acc[i][j] = (f32x4){0.f,0.f,0.f,0.f};
  int r16 = lane & 15, kg = lane >> 4;
  for (int kt=0; kt<KPAD/32; kt++){
    int k0 = kt*32;
    for (int c=0;c<2;c++){
      int id = c*256 + tid;            // 0..511
      int row = id >> 2, col = id & 3; // 4 x 16B chunks per 32-k row
      *(uint4*)&As[row*LDT + col*8] = *(const uint4*)&A[(size_t)(m0+row)*KPAD + k0 + col*8];
      *(uint4*)&Bs[row*LDT + col*8] = *(const uint4*)&B[(size_t)(n0+row)*KPAD + k0 + col*8];
    }
    __syncthreads();
    bf16x8 af[4], bfr[4];
    for (int i=0;i<4;i++) af[i]  = *(const bf16x8*)&As[(wm*64 + i*16 + r16)*LDT + kg*8];
    for (int j=0;j<4;j++) bfr[j] = *(const bf16x8*)&Bs[(wn*64 + j*16 + r16)*LDT + kg*8];
    for (int i=0;i<4;i++)
      for (int j=0;j<4;j++)
        acc[i][j] = __builtin_amdgcn_mfma_f32_16x16x32_bf16(af[i], bfr[j], acc[i][j], 0, 0, 0);
    __syncthreads();
  }
  // C/D layout (m89-verified): col = lane&15, row = (lane>>4)*4 + reg
  for (int j=0;j<4;j++){
    int col = n0 + wn*64 + j*16 + r16;
    if (col >= Nreal) continue;
    float bv = bias ? bias[col] : 0.f;
    for (int i=0;i<4;i++){
      int rbase = m0 + wm*64 + i*16 + kg*4;
      for (int r=0;r<4;r++){
        int row = rbase + r;
        if (row < Mreal) C[(size_t)row*ldc + col] = acc[i][j][r] + bv;
      }
    }
  }
}

// ---------------- LSTM recurrence: 20 independent waves, drained-flag exchange ----------------
// Wave s (block s, 64 threads) owns j-slice [16s,16s+16) x 4 gates x all 64 rows.
// Whh A-fragments resident in VGPRs (160). Per step:
//   XIH acc-preload (plain, issued pre-poll) -> poll 20 monotonic flags (batched) ->
//   B-frags loaded straight from LLC (8B agent atomic loads, 2-stage pipeline vs MFMA)
//   -> 160 MFMA -> activation -> publish h-slice (8B atomic stores) ->
//   s_waitcnt vmcnt(0) (per-wave drain to LLC) -> flag = t+2.
// Flag semantics: flag[s] = #h-vectors wave s published (h0 counts). Consumer step t
// needs flags >= t+1. 4-slot rotation safe: any wave at step t saw flags >= t, so all
// waves finished reading slot content h(t-4) long before it is overwritten.
// No barriers, no LDS, no sentinels, no fences.
__global__ __launch_bounds__(64,1) void recur_wave(
    const float* __restrict__ Xih, const u16* __restrict__ WA,
    const float* __restrict__ h0, const float* __restrict__ c0,
    uint32_t* hx, int* flags, u16* seq, float* hfin, float* cfin, int steps)
{
  int lane = threadIdx.x;
  int s = blockIdx.x;                 // j-slice 0..19
  int l15 = lane & 15, lk = lane >> 4;
  int jb = s*16 + lk*4;               // lane's output j-base (C layout)
  int jp0 = jb >> 1;                  // even -> 8B aligned

  // resident A-fragments: 160 VGPRs
  bf16x8 wfr[4][10];
  #pragma unroll
  for (int g=0; g<4; ++g)
    #pragma unroll
    for (int kc=0; kc<10; ++kc)
      wfr[g][kc] = *(const bf16x8*)&WA[(size_t)((s*4+g)*10 + kc)*512 + lane*8];

  // c init + publish h0 into slot 3, then flag=1
  f32x4 creg[4];
  #pragma unroll
  for (int nt=0; nt<4; ++nt){
    int row = nt*16 + l15;
    float hv4[4];
    #pragma unroll
    for (int r=0; r<4; ++r){
      int j = jb + r;
      creg[nt][r] = (j < EDIM) ? c0[row*EDIM + j] : 0.f;
      hv4[r]      = (j < EDIM) ? h0[row*EDIM + j] : 0.f;
    }
    uint32_t w0 = (uint32_t)f2bf(hv4[0]) | ((uint32_t)f2bf(hv4[1]) << 16);
    uint32_t w1 = (uint32_t)f2bf(hv4[2]) | ((uint32_t)f2bf(hv4[3]) << 16);
    uint64_t pk = (uint64_t)w0 | ((uint64_t)w1 << 32);
    __hip_atomic_store((uint64_t*)&hx[3*HXW + row*160 + jp0], pk,
                       __ATOMIC_RELAXED, __HIP_MEMORY_SCOPE_AGENT);
  }
  asm volatile("s_waitcnt vmcnt(0)" ::: "memory");
  if (lane == 0)
    __hip_atomic_store(&flags[s<<4], 1, __ATOMIC_RELAXED, __HIP_MEMORY_SCOPE_AGENT);

  for (int t=0; t<steps; ++t){
    // acc init = XIH (+bias folded) — plain loads issued before poll, hidden under it
    f32x4 acc[4][4];
    #pragma unroll
    for (int g=0; g<4; ++g)
      #pragma unroll
      for (int nt=0; nt<4; ++nt)
        acc[g][nt] = *(const f32x4*)&Xih[(size_t)((nt*16+l15)*steps + t)*NG + g*EDIM + jb];

    // poll all 20 flags (independent batched loads per retry)
    {
      int tgt = t + 1;
      for (;;){
        bool ok = true;
        #pragma unroll
        for (int w=0; w<NSL; ++w){
          int v = __hip_atomic_load(&flags[w<<4], __ATOMIC_RELAXED, __HIP_MEMORY_SCOPE_AGENT);
          ok &= (v >= tgt);
        }
        if (ok) break;
        __builtin_amdgcn_s_sleep(2);
      }
    }
    __builtin_amdgcn_sched_barrier(0);   // keep data loads after poll exit

    // B-fragments straight from LLC, 2-stage pipeline against MFMA
    const uint32_t* src = hx + (size_t)((t+3)&3)*HXW;
    auto load_hf = [&](bf16x8* dst, int kc){
      #pragma unroll
      for (int nt=0; nt<4; ++nt){
        int row = nt*16 + l15;
        const uint64_t* p = (const uint64_t*)(src + row*160 + kc*16 + lk*4);
        uint64_t a = __hip_atomic_load(p,   __ATOMIC_RELAXED, __HIP_MEMORY_SCOPE_AGENT);
        uint64_t b = __hip_atomic_load(p+1, __ATOMIC_RELAXED, __HIP_MEMORY_SCOPE_AGENT);
        union { uint64_t q[2]; bf16x8 v; } u; u.q[0] = a; u.q[1] = b;
        dst[nt] = u.v;
      }
    };
    bf16x8 hA[4], hB[4];
    load_hf(hA, 0);
    #pragma unroll
    for (int kc=0; kc<10; kc+=2){
      load_hf(hB, kc+1);
      #pragma unroll
      for (int g=0; g<4; ++g)
        #pragma unroll
        for (int nt=0; nt<4; ++nt)
          acc[g][nt] = __builtin_amdgcn_mfma_f32_16x16x32_bf16(wfr[g][kc], hA[nt], acc[g][nt], 0, 0, 0);
      if (kc+2 < 10) load_hf(hA, kc+2);
      #pragma unroll
      for (int g=0; g<4; ++g)
        #pragma unroll
        for (int nt=0; nt<4; ++nt)
          acc[g][nt] = __builtin_amdgcn_mfma_f32_16x16x32_bf16(wfr[g][kc+1], hB[nt], acc[g][nt], 0, 0, 0);
    }

    // activation + publish h(t) (critical path), then flag, then seq/finals
    int sw = t & 3;
    float hv[4][4];
    #pragma unroll
    for (int nt=0; nt<4; ++nt){
      int row = nt*16 + l15;
      #pragma unroll
      for (int r=0; r<4; ++r){
        float gi = acc[0][nt][r], gf = acc[1][nt][r];
        float gg = acc[2][nt][r], go = acc[3][nt][r];
        float c = sigm(gf)*creg[nt][r] + sigm(gi)*tanhf_(gg);
        creg[nt][r] = c;
        hv[nt][r] = sigm(go)*tanhf_(c);
      }
      if (t < steps-1){
        uint32_t w0 = (uint32_t)f2bf(hv[nt][0]) | ((uint32_t)f2bf(hv[nt][1]) << 16);
        uint32_t w1 = (uint32_t)f2bf(hv[nt][2]) | ((uint32_t)f2bf(hv[nt][3]) << 16);
        uint64_t pk = (uint64_t)w0 | ((uint64_t)w1 << 32);
        __hip_atomic_store((uint64_t*)&hx[(size_t)sw*HXW + row*160 + jp0], pk,
                           __ATOMIC_RELAXED, __HIP_MEMORY_SCOPE_AGENT);
      }
    }
    if (t < steps-1){
      asm volatile("s_waitcnt vmcnt(0)" ::: "memory");
      if (lane == 0)
        __hip_atomic_store(&flags[s<<4], t+2, __ATOMIC_RELAXED, __HIP_MEMORY_SCOPE_AGENT);
    }
    // off-critical-path outputs
    if (seq){
      #pragma unroll
      for (int nt=0; nt<4; ++nt){
        int row = nt*16 + l15;
        size_t sb = (size_t)(row*steps + t)*KPAD + jb;
        if (jb + 3 < EDIM){
          uint2 q;
          q.x = (uint32_t)f2bf(hv[nt][0]) | ((uint32_t)f2bf(hv[nt][1]) << 16);
          q.y = (uint32_t)f2bf(hv[nt][2]) | ((uint32_t)f2bf(hv[nt][3]) << 16);
          *(uint2*)&seq[sb] = q;
        } else {
          #pragma unroll
          for (int r=0; r<4; ++r) if (jb + r < EDIM) seq[sb + r] = f2bf(hv[nt][r]);
        }
      }
    }
    if (t == steps-1 && hfin){
      #pragma unroll
      for (int nt=0; nt<4; ++nt){
        int row = nt*16 + l15;
        #pragma unroll
        for (int r=0; r<4; ++r) if (jb + r < EDIM){
          hfin[row*EDIM + jb + r] = hv[nt][r];
          cfin[row*EDIM + jb + r] = creg[nt][r];
        }
      }
    }
  }
}

// ---------------- fused log_softmax (in-place on d_out) + masked NLL ----------------
__global__ __launch_bounds__(256) void lsm_loss(float* __restrict__ out, const int* __restrict__ zh,
                                                float* __restrict__ lacc){
  int row = blockIdx.x;
  int tid = threadIdx.x;
  __shared__ float buf[ZHV];
  __shared__ float red[8];
  float* p = out + (size_t)row*ZHV;
  float m = -1e30f;
  for (int i=tid; i<ZHV; i+=256){ float v = p[i]; buf[i] = v; m = fmaxf(m, v); }
  for (int off=32; off; off>>=1) m = fmaxf(m, __shfl_xor(m, off));
  if ((tid&63)==0) red[tid>>6] = m;
  __syncthreads();
  m = fmaxf(fmaxf(red[0],red[1]), fmaxf(red[2],red[3]));
  float s = 0.f;
  for (int i=tid; i<ZHV; i+=256) s += __expf(buf[i]-m);
  for (int off=32; off; off>>=1) s += __shfl_xor(s, off);
  if ((tid&63)==0) red[4+(tid>>6)] = s;
  __syncthreads();
  s = red[4]+red[5]+red[6]+red[7];
  float lse = m + __logf(s);
  for (int i=tid; i<ZHV; i+=256) p[i] = buf[i] - lse;
  if (tid == 0){
    int b = row / SDEC, t = row - b*SDEC;
    int tgt = zh[b*SENC + t + 1];
    if (tgt != 0){
      atomicAdd(&lacc[0], -(buf[tgt] - lse));
      atomicAdd(&lacc[1], 1.0f);
    }
  }
}

__global__ void fin_loss(float* out, const float* lacc){
  out[(size_t)DROWS*ZHV] = lacc[0]/lacc[1];
}

// ---------------- host ----------------
extern "C" void kernel_launch(void* const* d_in, const int* in_sizes, int n_in,
                              void* d_out, int out_size, void* d_ws, size_t ws_size,
                              hipStream_t stream){
  const int*   en_in   = (const int*)d_in[0];
  const int*   zh_in   = (const int*)d_in[1];
  const float* en_emb  = (const float*)d_in[2];
  const float* zh_emb  = (const float*)d_in[3];
  const float* enc_Wih = (const float*)d_in[4];
  const float* enc_Whh = (const float*)d_in[5];
  const float* enc_b   = (const float*)d_in[6];
  const float* dec_Wih = (const float*)d_in[7];
  const float* dec_Whh = (const float*)d_in[8];
  const float* dec_b   = (const float*)d_in[9];
  const float* fc_W    = (const float*)d_in[10];
  const float* fc_b    = (const float*)d_in[11];
  float* out = (float*)d_out;
  char* ws = (char*)d_ws;

  size_t o = 0;
  auto alloc = [&](size_t b){ size_t r = o; o = (o + b + 255) & ~(size_t)255; return r; };
  size_t wa[4], wih[4];
  for (int i=0;i<4;i++) wa[i]  = alloc((size_t)NSL*4*10*512*2); // MFMA A-frag Whh bf16
  for (int i=0;i<4;i++) wih[i] = alloc((size_t)1280*KPAD*2);    // Wih as B operand
  size_t fcw  = alloc((size_t)12032*KPAD*2);
  size_t xen  = alloc((size_t)MPAD*KPAD*2);
  size_t xl1e = alloc((size_t)MPAD*KPAD*2);
  size_t xzh  = alloc((size_t)MPAD*KPAD*2);
  size_t xl1d = alloc((size_t)MPAD*KPAD*2);
  size_t xl2d = alloc((size_t)MPAD*KPAD*2);
  size_t xih  = alloc(((size_t)MPAD*NG + 64)*4);   // +64 floats: padded-slice overread
  size_t hxo  = alloc((size_t)4*4*HXW*4);          // 4 layers x 4 slots x 40KB
  size_t flg  = alloc((size_t)4*NSL*16*4);         // 4 layers x 20 flags (64B padded)
  size_t hfin = alloc((size_t)2*NB*EDIM*4);
  size_t cfin = alloc((size_t)2*NB*EDIM*4);
  size_t hz   = alloc((size_t)NB*EDIM*4);
  size_t lac  = alloc(256);
  size_t used = o;
  if (ws_size < used) return;  // fail loudly (output stays poisoned)

  zero_kernel<<<2048,256,0,stream>>>((float4*)ws, (long)(used/16));

  for (int l=0;l<2;l++){
    build_wa<<<1600,256,0,stream>>>(enc_Whh + (size_t)l*NG*EDIM, (u16*)(ws+wa[l]));
    build_wa<<<1600,256,0,stream>>>(dec_Whh + (size_t)l*NG*EDIM, (u16*)(ws+wa[2+l]));
    build_b<<<1407,256,0,stream>>>(enc_Wih + (size_t)l*NG*EDIM, (u16*)(ws+wih[l]),   NG);
    build_b<<<1407,256,0,stream>>>(dec_Wih + (size_t)l*NG*EDIM, (u16*)(ws+wih[2+l]), NG);
  }
  build_b<<<(ZHV*EDIM+255)/256,256,0,stream>>>(fc_W, (u16*)(ws+fcw), ZHV);
  embed_en<<<(MPAD*EDIM+255)/256,256,0,stream>>>(en_in, en_emb, (u16*)(ws+xen));
  embed_zh<<<(DROWS*EDIM+255)/256,256,0,stream>>>(zh_in, zh_emb, (u16*)(ws+xzh));

  float* XIH = (float*)(ws+xih);
  uint32_t* HX = (uint32_t*)(ws+hxo);
  int* FLG   = (int*)(ws+flg);
  float* LAC = (float*)(ws+lac);
  float* HF  = (float*)(ws+hfin);
  float* CF  = (float*)(ws+cfin);
  float* HZ  = (float*)(ws+hz);

  // encoder layer 1  (LSTM bias folded into XIH via gemm bias)
  gemm_nt<<<dim3(10,32),256,0,stream>>>((u16*)(ws+xen), (u16*)(ws+wih[0]), XIH, NG, MPAD, NG, enc_b);
  recur_wave<<<NSL,64,0,stream>>>(XIH, (u16*)(ws+wa[0]), HZ, HZ, HX, FLG, (u16*)(ws+xl1e), HF, CF, SENC);
  // encoder layer 2 (hidden sequence unused; only finals kept)
  gemm_nt<<<dim3(10,32),256,0,stream>>>((u16*)(ws+xl1e), (u16*)(ws+wih[1]), XIH, NG, MPAD, NG, enc_b+NG);
  recur_wave<<<NSL,64,0,stream>>>(XIH, (u16*)(ws+wa[1]), HZ, HZ, HX+(size_t)4*HXW, FLG+NSL*16, nullptr, HF+NB*EDIM, CF+NB*EDIM, SENC);
  // decoder layer 1
  gemm_nt<<<dim3(10,32),256,0,stream>>>((u16*)(ws+xzh), (u16*)(ws+wih[2]), XIH, NG, MPAD, NG, dec_b);
  recur_wave<<<NSL,64,0,stream>>>(XIH, (u16*)(ws+wa[2]), HF, CF, HX+(size_t)8*HXW, FLG+2*NSL*16, (u16*)(ws+xl1d), nullptr, nullptr, SDEC);
  // decoder layer 2
  gemm_nt<<<dim3(10,32),256,0,stream>>>((u16*)(ws+xl1d), (u16*)(ws+wih[3]), XIH, NG, MPAD, NG, dec_b+NG);
  recur_wave<<<NSL,64,0,stream>>>(XIH, (u16*)(ws+wa[3]), HF+NB*EDIM, CF+NB*EDIM, HX+(size_t)12*HXW, FLG+3*NSL*16, (u16*)(ws+xl2d), nullptr, nullptr, SDEC);
  // FC head -> logits straight into d_out
  gemm_nt<<<dim3(94,32),256,0,stream>>>((u16*)(ws+xl2d), (u16*)(ws+fcw), out, ZHV, DROWS, ZHV, fc_b);
  // in-place log_softmax + masked NLL
  lsm_loss<<<DROWS,256,0,stream>>>(out, zh_in, LAC);
  fin_loss<<<1,1,0,stream>>>(out, LAC);
}